// Round 6
// baseline (82.038 us; speedup 1.0000x reference)
//
#include <hip/hip_runtime.h>

#define B_    4
#define CIN_  64
#define H_    128
#define W_    128
#define COUT_ 64
#define HW    (H_*W_)
#define KPOS  576

typedef __attribute__((ext_vector_type(8))) short bf16x8;
typedef __attribute__((ext_vector_type(4))) short bf16x4;
typedef __attribute__((ext_vector_type(4))) float f32x4;
typedef __attribute__((ext_vector_type(4))) _Float16 f16x4;

static __device__ __forceinline__ unsigned short f2bf(float f) {
    union { float f; unsigned u; } a; a.f = f;
    unsigned r = a.u + 0x7fffu + ((a.u >> 16) & 1u);   // RNE
    return (unsigned short)(r >> 16);
}
static __device__ __forceinline__ float bfl(unsigned u) {   // low bf16 -> f32
    union { unsigned x; float f; } a; a.x = u << 16; return a.f;
}
static __device__ __forceinline__ float bfh(unsigned u) {   // high bf16 -> f32
    union { unsigned x; float f; } a; a.x = u & 0xffff0000u; return a.f;
}
static __device__ __forceinline__ unsigned cvt_pk_bf16(float lo, float hi) {
    unsigned r;
    asm("v_cvt_pk_bf16_f32 %0, %1, %2" : "=v"(r) : "v"(lo), "v"(hi));
    return r;
}

#define XT_USHORTS 4194304                       // B*HW*64 NHWC bf16 image
#define WP_USHORTS 36864                         // wt[k][co][c]
#define META_CNT   (B_*9*HW)                     // 589824
#define OFFS_BYTE  ((XT_USHORTS + WP_USHORTS) * 2)        // 8462336
#define WTS_BYTE   (OFFS_BYTE + META_CNT * 4)             // 10821632
#define WS_NEED3   ((size_t)(WTS_BYTE + META_CNT * 8))    // ~15.5 MB

// ================= fused prep: xpose | meta | weight in one launch =========
__global__ __launch_bounds__(256)
void prep_all(const float* __restrict__ x,
              const float* __restrict__ offset,
              const float* __restrict__ mask,
              const float* __restrict__ w,
              unsigned short* __restrict__ xT,
              unsigned short* __restrict__ wt,
              unsigned* __restrict__ mOffs,
              f16x4* __restrict__ mWts)
{
    const int bid = blockIdx.x;
    const int t   = threadIdx.x;

    if (bid < 512) {
        // ---- x NCHW f32 -> NHWC bf16 (one (b,y) row per block) ----
        __shared__ unsigned short ld[64 * 132];
        const int b = bid >> 7;
        const int y = bid & 127;
        const float* src = x + (size_t)b * 64 * HW + y * W_;
        #pragma unroll
        for (int i = 0; i < 8; ++i) {
            const int e4 = (t + i * 256) * 4;
            const int c  = e4 >> 7;
            const int x0 = e4 & 127;
            const float4 v = *(const float4*)(src + (size_t)c * HW + x0);
            unsigned short* d = &ld[c * 132 + x0];
            d[0] = f2bf(v.x); d[1] = f2bf(v.y); d[2] = f2bf(v.z); d[3] = f2bf(v.w);
        }
        __syncthreads();
        unsigned short* dst = xT + ((size_t)b * HW + (size_t)y * W_) * 64;
        #pragma unroll
        for (int i = 0; i < 4; ++i) {
            const int o    = (t + i * 256) * 8;
            const int xcol = o >> 6;
            const int c0   = o & 63;
            union { bf16x8 v; unsigned short u[8]; } pk;
            #pragma unroll
            for (int j = 0; j < 8; ++j) pk.u[j] = ld[(c0 + j) * 132 + xcol];
            *(bf16x8*)(dst + o) = pk.v;
        }
    } else if (bid < 2816) {
        // ---- sampling metadata per (b,tap,pixel) ----
        const int i  = (bid - 512) * 256 + t;
        const int gp = i & (HW - 1);
        const int bk = i >> 14;              // b*9 + k
        const int b  = bk / 9;
        const int k  = bk - b * 9;
        const int ho = gp >> 7, wo = gp & 127;
        const float dy = offset[(size_t)(b * 18 + 2 * k) * HW + gp];
        const float dx = offset[(size_t)(b * 18 + 2 * k + 1) * HW + gp];
        const float mm = mask[(size_t)bk * HW + gp];
        const float py  = dy + (float)(k / 3) + (float)(ho - 1);   // PAD=1
        const float pxx = dx + (float)(k % 3) + (float)(wo - 1);
        const float y0f = floorf(py), x0f = floorf(pxx);
        const float wy = py - y0f, wx = pxx - x0f;
        const int y0 = (int)y0f, x0 = (int)x0f;
        const int y1 = y0 + 1,  x1 = x0 + 1;
        const bool vy0 = (y0 >= 0) & (y0 < H_), vy1 = (y1 >= 0) & (y1 < H_);
        const bool vx0 = (x0 >= 0) & (x0 < W_), vx1 = (x1 >= 0) & (x1 < W_);
        const int cy0 = min(max(y0, 0), H_-1), cy1 = min(max(y1, 0), H_-1);
        const int cx0 = min(max(x0, 0), W_-1), cx1 = min(max(x1, 0), W_-1);
        mOffs[i] = (unsigned)cy0 | ((unsigned)cy1 << 8)
                 | ((unsigned)cx0 << 16) | ((unsigned)cx1 << 24);
        f16x4 wv;
        wv[0] = (_Float16)((vy0 && vx0) ? (1.f - wy) * (1.f - wx) * mm : 0.f);
        wv[1] = (_Float16)((vy0 && vx1) ? (1.f - wy) * wx * mm         : 0.f);
        wv[2] = (_Float16)((vy1 && vx0) ? wy * (1.f - wx) * mm         : 0.f);
        wv[3] = (_Float16)((vy1 && vx1) ? wy * wx * mm                 : 0.f);
        mWts[i] = wv;
    } else {
        // ---- weight -> bf16, tap-major: wt[k][co][c] ----
        const int i = (bid - 2816) * 256 + t;
        if (i < 9 * 64 * 64) {
            const int k  = i >> 12;
            const int r  = i & 4095;
            const int co = r >> 6;
            const int c  = r & 63;
            wt[i] = f2bf(w[co * KPOS + c * 9 + k]);
        }
    }
}

// ================= main: fully register-resident, ZERO barriers ============
// lane = g*16 + pxl : pxl = pixel (M row), g = channel-oct -> the bilinear
// result IS the MFMA A-fragment; B-frags load straight from wprep (L2-hot).
__global__ __launch_bounds__(256, 3)
void dcn_reg(const unsigned short* __restrict__ xT,
             const unsigned* __restrict__ mOffs,
             const f16x4* __restrict__ mWts,
             const float* __restrict__ bias,
             const unsigned short* __restrict__ wprep,
             float* __restrict__ out)
{
    const int t    = threadIdx.x;
    const int bid  = blockIdx.x;
    const int wk   = ((bid & 7) << 7) | (bid >> 3);   // XCD-chunked swizzle
    const int xh   = wk & 1;
    const int ho   = (wk >> 1) & 127;
    const int b    = wk >> 8;
    const int cq   = t >> 6;
    const int lane = t & 63;
    const int pxl  = lane & 15;          // pixel within wave tile (M row)
    const int g8   = (lane >> 4) * 8;    // channel-oct offset (k-frag col)

    f32x4 acc[4];
    #pragma unroll
    for (int i = 0; i < 4; ++i) acc[i] = (f32x4){0.f, 0.f, 0.f, 0.f};

    const unsigned short* xTb = xT + (size_t)b * HW * 64;
    const int gp    = ho * W_ + xh * 64 + cq * 16 + pxl;
    const int mbase = (b * 9) << 14;

    // ---- all 9 taps' metadata up front (27 VGPR, breaks meta->gather chain)
    unsigned pk9[9]; f16x4 wh9[9];
    #pragma unroll
    for (int k = 0; k < 9; ++k) {
        const int mi = mbase + (k << 14) + gp;
        pk9[k] = mOffs[mi];
        wh9[k] = mWts[mi];
    }

    #pragma unroll
    for (int k = 0; k < 9; ++k) {
        // ---- gather this lane's pixel corners at its channel oct ----
        const unsigned pk = pk9[k];
        const int y0 = (pk & 255) << 7,         y1 = ((pk >> 8) & 255) << 7;
        const int x0 = (pk >> 16) & 255,        x1 = (int)(pk >> 24);
        const int p00 = ((y0 | x0) << 6) + g8,  p01 = ((y0 | x1) << 6) + g8;
        const int p10 = ((y1 | x0) << 6) + g8,  p11 = ((y1 | x1) << 6) + g8;
        bf16x8 c00a = *(const bf16x8*)(xTb + p00);
        bf16x8 c01a = *(const bf16x8*)(xTb + p01);
        bf16x8 c10a = *(const bf16x8*)(xTb + p10);
        bf16x8 c11a = *(const bf16x8*)(xTb + p11);
        bf16x8 c00b = *(const bf16x8*)(xTb + p00 + 32);
        bf16x8 c01b = *(const bf16x8*)(xTb + p01 + 32);
        bf16x8 c10b = *(const bf16x8*)(xTb + p10 + 32);
        bf16x8 c11b = *(const bf16x8*)(xTb + p11 + 32);

        // ---- B fragments straight from wprep (no LDS) ----
        const unsigned short* wp = wprep + k * 4096 + pxl * 64 + g8;
        bf16x8 bf0[4], bf1[4];
        #pragma unroll
        for (int nt = 0; nt < 4; ++nt) {
            bf0[nt] = *(const bf16x8*)(wp + nt * 1024);
            bf1[nt] = *(const bf16x8*)(wp + nt * 1024 + 32);
        }

        const float w0 = (float)wh9[k][0];
        const float w1 = (float)wh9[k][1];
        const float w2 = (float)wh9[k][2];
        const float w3 = (float)wh9[k][3];

        // ---- bilinear combine -> A fragments (in-lane, no LDS) ----
        union { bf16x8 v; unsigned u[4]; } a0, a1;
        {
            const unsigned* u0 = (const unsigned*)&c00a;
            const unsigned* u1 = (const unsigned*)&c01a;
            const unsigned* u2 = (const unsigned*)&c10a;
            const unsigned* u3 = (const unsigned*)&c11a;
            #pragma unroll
            for (int j = 0; j < 4; ++j) {
                const float lo = w0*bfl(u0[j]) + w1*bfl(u1[j])
                               + w2*bfl(u2[j]) + w3*bfl(u3[j]);
                const float hi = w0*bfh(u0[j]) + w1*bfh(u1[j])
                               + w2*bfh(u2[j]) + w3*bfh(u3[j]);
                a0.u[j] = cvt_pk_bf16(lo, hi);
            }
        }
        {
            const unsigned* u0 = (const unsigned*)&c00b;
            const unsigned* u1 = (const unsigned*)&c01b;
            const unsigned* u2 = (const unsigned*)&c10b;
            const unsigned* u3 = (const unsigned*)&c11b;
            #pragma unroll
            for (int j = 0; j < 4; ++j) {
                const float lo = w0*bfl(u0[j]) + w1*bfl(u1[j])
                               + w2*bfl(u2[j]) + w3*bfl(u3[j]);
                const float hi = w0*bfh(u0[j]) + w1*bfh(u1[j])
                               + w2*bfh(u2[j]) + w3*bfh(u3[j]);
                a1.u[j] = cvt_pk_bf16(lo, hi);
            }
        }

        // ---- 8 MFMAs, pure register dataflow ----
        #pragma unroll
        for (int nt = 0; nt < 4; ++nt)
            acc[nt] = __builtin_amdgcn_mfma_f32_16x16x32_bf16(a0.v, bf0[nt], acc[nt], 0, 0, 0);
        #pragma unroll
        for (int nt = 0; nt < 4; ++nt)
            acc[nt] = __builtin_amdgcn_mfma_f32_16x16x32_bf16(a1.v, bf1[nt], acc[nt], 0, 0, 0);
    }

    // ---- epilogue: D col = lane&15 (co-sub), row = (lane>>4)*4+j (pixel) ----
    const int px0 = cq * 16 + (lane >> 4) * 4;
    #pragma unroll
    for (int nt = 0; nt < 4; ++nt) {
        const int co = nt * 16 + (lane & 15);
        const float bb = bias[co];
        float4 r;
        r.x = acc[nt][0] + bb;
        r.y = acc[nt][1] + bb;
        r.z = acc[nt][2] + bb;
        r.w = acc[nt][3] + bb;
        *(float4*)&out[(((size_t)b * COUT_ + co) * H_ + ho) * W_ + xh * 64 + px0] = r;
    }
}

// ================= fallback path (ws too small): R4 kernels =================
__global__ __launch_bounds__(256)
void xpose_bf16(const float* __restrict__ x, unsigned short* __restrict__ xT)
{
    __shared__ unsigned short ld[64 * 132];
    const int t   = threadIdx.x;
    const int blk = blockIdx.x;
    const int b   = blk >> 7;
    const int y   = blk & 127;
    const float* src = x + (size_t)b * 64 * HW + y * W_;
    #pragma unroll
    for (int i = 0; i < 8; ++i) {
        const int e4 = (t + i * 256) * 4;
        const int c  = e4 >> 7;
        const int x0 = e4 & 127;
        const float4 v = *(const float4*)(src + (size_t)c * HW + x0);
        unsigned short* d = &ld[c * 132 + x0];
        d[0] = f2bf(v.x); d[1] = f2bf(v.y); d[2] = f2bf(v.z); d[3] = f2bf(v.w);
    }
    __syncthreads();
    unsigned short* dst = xT + ((size_t)b * HW + (size_t)y * W_) * 64;
    #pragma unroll
    for (int i = 0; i < 4; ++i) {
        const int o    = (t + i * 256) * 8;
        const int xcol = o >> 6;
        const int c0   = o & 63;
        union { bf16x8 v; unsigned short u[8]; } pk;
        #pragma unroll
        for (int j = 0; j < 8; ++j) pk.u[j] = ld[(c0 + j) * 132 + xcol];
        *(bf16x8*)(dst + o) = pk.v;
    }
}

__global__ void prep_weight_bf16(const float* __restrict__ w,
                                 unsigned short* __restrict__ wt)
{
    const int i = blockIdx.x * 256 + threadIdx.x;
    if (i >= 9 * 64 * 64) return;
    const int k  = i >> 12;
    const int r  = i & 4095;
    const int co = r >> 6;
    const int c  = r & 63;
    wt[i] = f2bf(w[co * KPOS + c * 9 + k]);
}

__global__ __launch_bounds__(256, 4)
void dcn_mfma_nhwc(const unsigned short* __restrict__ xT,
                   const float* __restrict__ offset,
                   const float* __restrict__ mask,
                   const float* __restrict__ bias,
                   const unsigned short* __restrict__ wprep,
                   float* __restrict__ out)
{
    __shared__ unsigned short vP[2][64][72];
    __shared__ unsigned short Wk[2][64][72];
    const int t   = threadIdx.x;
    const int bid = blockIdx.x;
    const int wk  = ((bid & 7) << 7) | (bid >> 3);
    const int xh  = wk & 1;
    const int ho  = (wk >> 1) & 127;
    const int b   = wk >> 8;
    const int cq  = t >> 6;
    const int lane = t & 63;
    const int px_sub = lane >> 4;
    const int c4     = lane & 15;
    f32x4 acc[4];
    #pragma unroll
    for (int i = 0; i < 4; ++i) acc[i] = (f32x4){0.f, 0.f, 0.f, 0.f};
    const unsigned short* xTb = xT + (size_t)b * HW * 64;

    auto stage = [&](int k, int s) {
        int   idxs[4][4];
        float wts [4][4];
        #pragma unroll
        for (int it = 0; it < 4; ++it) {
            const int pl = (cq << 4) | (it << 2) | px_sub;
            const int wo = xh * 64 + pl;
            const int obase = ((b * 18 + 2 * k) * H_ + ho) * W_ + wo;
            const float dy = offset[obase];
            const float dx = offset[obase + HW];
            const float mm = mask[((b * 9 + k) * H_ + ho) * W_ + wo];
            const float py  = dy + (float)(k / 3) + (float)(ho - 1);
            const float pxx = dx + (float)(k % 3) + (float)(wo - 1);
            const float y0f = floorf(py), x0f = floorf(pxx);
            const float wy = py - y0f, wx = pxx - x0f;
            const int y0 = (int)y0f, x0 = (int)x0f;
            const int y1 = y0 + 1,  x1 = x0 + 1;
            const bool vy0 = (y0 >= 0) & (y0 < H_), vy1 = (y1 >= 0) & (y1 < H_);
            const bool vx0 = (x0 >= 0) & (x0 < W_), vx1 = (x1 >= 0) & (x1 < W_);
            const int cy0 = min(max(y0, 0), H_-1), cy1 = min(max(y1, 0), H_-1);
            const int cx0 = min(max(x0, 0), W_-1), cx1 = min(max(x1, 0), W_-1);
            idxs[it][0] = (cy0 * W_ + cx0) << 6;
            idxs[it][1] = (cy0 * W_ + cx1) << 6;
            idxs[it][2] = (cy1 * W_ + cx0) << 6;
            idxs[it][3] = (cy1 * W_ + cx1) << 6;
            wts[it][0] = (vy0 && vx0) ? (1.f - wy) * (1.f - wx) * mm : 0.f;
            wts[it][1] = (vy0 && vx1) ? (1.f - wy) * wx * mm         : 0.f;
            wts[it][2] = (vy1 && vx0) ? wy * (1.f - wx) * mm         : 0.f;
            wts[it][3] = (vy1 && vx1) ? wy * wx * mm                 : 0.f;
        }
        bf16x4 cr[4][4];
        #pragma unroll
        for (int it = 0; it < 4; ++it)
            #pragma unroll
            for (int cn = 0; cn < 4; ++cn)
                cr[it][cn] = *(const bf16x4*)(xTb + idxs[it][cn] + (c4 << 2));
        #pragma unroll
        for (int q = 0; q < 2; ++q) {
            const int j  = q * 2048 + t * 8;
            *(bf16x8*)&Wk[s][j >> 6][j & 63] = *(const bf16x8*)(wprep + k * 4096 + j);
        }
        #pragma unroll
        for (int it = 0; it < 4; ++it) {
            const int pl = (cq << 4) | (it << 2) | px_sub;
            union { bf16x4 v; unsigned short u[4]; } pk;
            #pragma unroll
            for (int j = 0; j < 4; ++j) {
                union { short s; unsigned short u; } s0{cr[it][0][j]}, s1{cr[it][1][j]},
                                                     s2{cr[it][2][j]}, s3{cr[it][3][j]};
                const float v = wts[it][0] * bfl(s0.u) + wts[it][1] * bfl(s1.u)
                              + wts[it][2] * bfl(s2.u) + wts[it][3] * bfl(s3.u);
                pk.u[j] = f2bf(v);
            }
            *(bf16x4*)&vP[s][pl][c4 << 2] = pk.v;
        }
    };
    auto domfma = [&](int s) {
        const int ra = cq * 16 + (lane & 15);
        const int kc = (lane >> 4) * 8;
        #pragma unroll
        for (int ks = 0; ks < 2; ++ks) {
            const int kcol = ks * 32 + kc;
            const bf16x8 a = *(const bf16x8*)&vP[s][ra][kcol];
            #pragma unroll
            for (int nt = 0; nt < 4; ++nt) {
                const bf16x8 bb = *(const bf16x8*)&Wk[s][nt * 16 + (lane & 15)][kcol];
                acc[nt] = __builtin_amdgcn_mfma_f32_16x16x32_bf16(a, bb, acc[nt], 0, 0, 0);
            }
        }
    };
    stage(0, 0);
    __syncthreads();
    for (int k = 0; k < 9; ++k) {
        const int s = k & 1;
        if (k < 8) stage(k + 1, s ^ 1);
        domfma(s);
        __syncthreads();
    }
    const int px0 = cq * 16 + (lane >> 4) * 4;
    #pragma unroll
    for (int nt = 0; nt < 4; ++nt) {
        const int co = nt * 16 + (lane & 15);
        const float bb = bias[co];
        float4 r;
        r.x = acc[nt][0] + bb;
        r.y = acc[nt][1] + bb;
        r.z = acc[nt][2] + bb;
        r.w = acc[nt][3] + bb;
        *(float4*)&out[(((size_t)b * COUT_ + co) * H_ + ho) * W_ + xh * 64 + px0] = r;
    }
}

extern "C" void kernel_launch(void* const* d_in, const int* in_sizes, int n_in,
                              void* d_out, int out_size, void* d_ws, size_t ws_size,
                              hipStream_t stream)
{
    const float* x      = (const float*)d_in[0];
    const float* offset = (const float*)d_in[1];
    const float* mask   = (const float*)d_in[2];
    const float* weight = (const float*)d_in[3];
    const float* bias   = (const float*)d_in[4];
    float* out = (float*)d_out;

    dim3 block(256);
    dim3 grid(B_ * H_ * 2);

    unsigned short* xT    = (unsigned short*)d_ws;
    unsigned short* wprep = xT + XT_USHORTS;

    if (ws_size >= WS_NEED3) {
        unsigned* mOffs = (unsigned*)((char*)d_ws + OFFS_BYTE);
        f16x4*    mWts  = (f16x4*)  ((char*)d_ws + WTS_BYTE);
        prep_all<<<dim3(2960), block, 0, stream>>>(x, offset, mask, weight,
                                                   xT, wprep, mOffs, mWts);
        dcn_reg<<<grid, block, 0, stream>>>(xT, mOffs, mWts, bias, wprep, out);
    } else {
        xpose_bf16<<<dim3(B_ * H_), block, 0, stream>>>(x, xT);
        prep_weight_bf16<<<dim3(144), block, 0, stream>>>(weight, wprep);
        dcn_mfma_nhwc<<<grid, block, 0, stream>>>(xT, offset, mask, bias, wprep, out);
    }
}

// Round 7
// 66.860 us; speedup vs baseline: 1.2270x; 1.2270x over previous
//
#include <hip/hip_runtime.h>

#define B_    4
#define CIN_  64
#define H_    128
#define W_    128
#define COUT_ 64
#define HW    (H_*W_)
#define KPOS  576

typedef __attribute__((ext_vector_type(8))) short bf16x8;
typedef __attribute__((ext_vector_type(4))) short bf16x4;
typedef __attribute__((ext_vector_type(4))) float f32x4;
typedef __attribute__((ext_vector_type(4))) _Float16 f16x4;

static __device__ __forceinline__ unsigned short f2bf(float f) {
    union { float f; unsigned u; } a; a.f = f;
    unsigned r = a.u + 0x7fffu + ((a.u >> 16) & 1u);   // RNE
    return (unsigned short)(r >> 16);
}
static __device__ __forceinline__ float bfl(unsigned u) {   // low bf16 -> f32
    union { unsigned x; float f; } a; a.x = u << 16; return a.f;
}
static __device__ __forceinline__ float bfh(unsigned u) {   // high bf16 -> f32
    union { unsigned x; float f; } a; a.x = u & 0xffff0000u; return a.f;
}
static __device__ __forceinline__ unsigned cvt_pk_bf16(float lo, float hi) {
    unsigned r;
    asm("v_cvt_pk_bf16_f32 %0, %1, %2" : "=v"(r) : "v"(lo), "v"(hi));
    return r;
}

#define XT_USHORTS 4194304                       // B*HW*64 NHWC bf16 image
#define WP_USHORTS 36864                         // wt2[k][p][co][32c]
#define META_CNT   (B_*9*HW)                     // 589824
#define OFFS_BYTE  ((XT_USHORTS + WP_USHORTS) * 2)        // 8462336
#define WTS_BYTE   (OFFS_BYTE + META_CNT * 4)             // 10821632
#define WS_NEED3   ((size_t)(WTS_BYTE + META_CNT * 8))    // ~15.5 MB

// ================= fused prep: xpose | meta | weight in one launch =========
__global__ __launch_bounds__(256)
void prep_all(const float* __restrict__ x,
              const float* __restrict__ offset,
              const float* __restrict__ mask,
              const float* __restrict__ w,
              unsigned short* __restrict__ xT,
              unsigned short* __restrict__ wt,
              unsigned* __restrict__ mOffs,
              f16x4* __restrict__ mWts)
{
    const int bid = blockIdx.x;
    const int t   = threadIdx.x;

    if (bid < 512) {
        // ---- x NCHW f32 -> NHWC bf16 (one (b,y) row per block) ----
        __shared__ unsigned short ld[64 * 132];
        const int b = bid >> 7;
        const int y = bid & 127;
        const float* src = x + (size_t)b * 64 * HW + y * W_;
        #pragma unroll
        for (int i = 0; i < 8; ++i) {
            const int e4 = (t + i * 256) * 4;
            const int c  = e4 >> 7;
            const int x0 = e4 & 127;
            const float4 v = *(const float4*)(src + (size_t)c * HW + x0);
            unsigned short* d = &ld[c * 132 + x0];
            d[0] = f2bf(v.x); d[1] = f2bf(v.y); d[2] = f2bf(v.z); d[3] = f2bf(v.w);
        }
        __syncthreads();
        unsigned short* dst = xT + ((size_t)b * HW + (size_t)y * W_) * 64;
        #pragma unroll
        for (int i = 0; i < 4; ++i) {
            const int o    = (t + i * 256) * 8;
            const int xcol = o >> 6;
            const int c0   = o & 63;
            union { bf16x8 v; unsigned short u[8]; } pk;
            #pragma unroll
            for (int j = 0; j < 8; ++j) pk.u[j] = ld[(c0 + j) * 132 + xcol];
            *(bf16x8*)(dst + o) = pk.v;
        }
    } else if (bid < 2816) {
        // ---- sampling metadata per (b,tap,pixel) ----
        const int i  = (bid - 512) * 256 + t;
        const int gp = i & (HW - 1);
        const int bk = i >> 14;              // b*9 + k
        const int b  = bk / 9;
        const int k  = bk - b * 9;
        const int ho = gp >> 7, wo = gp & 127;
        const float dy = offset[(size_t)(b * 18 + 2 * k) * HW + gp];
        const float dx = offset[(size_t)(b * 18 + 2 * k + 1) * HW + gp];
        const float mm = mask[(size_t)bk * HW + gp];
        const float py  = dy + (float)(k / 3) + (float)(ho - 1);   // PAD=1
        const float pxx = dx + (float)(k % 3) + (float)(wo - 1);
        const float y0f = floorf(py), x0f = floorf(pxx);
        const float wy = py - y0f, wx = pxx - x0f;
        const int y0 = (int)y0f, x0 = (int)x0f;
        const int y1 = y0 + 1,  x1 = x0 + 1;
        const bool vy0 = (y0 >= 0) & (y0 < H_), vy1 = (y1 >= 0) & (y1 < H_);
        const bool vx0 = (x0 >= 0) & (x0 < W_), vx1 = (x1 >= 0) & (x1 < W_);
        const int cy0 = min(max(y0, 0), H_-1), cy1 = min(max(y1, 0), H_-1);
        const int cx0 = min(max(x0, 0), W_-1), cx1 = min(max(x1, 0), W_-1);
        mOffs[i] = (unsigned)cy0 | ((unsigned)cy1 << 8)
                 | ((unsigned)cx0 << 16) | ((unsigned)cx1 << 24);
        f16x4 wv;
        wv[0] = (_Float16)((vy0 && vx0) ? (1.f - wy) * (1.f - wx) * mm : 0.f);
        wv[1] = (_Float16)((vy0 && vx1) ? (1.f - wy) * wx * mm         : 0.f);
        wv[2] = (_Float16)((vy1 && vx0) ? wy * (1.f - wx) * mm         : 0.f);
        wv[3] = (_Float16)((vy1 && vx1) ? wy * wx * mm                 : 0.f);
        mWts[i] = wv;
    } else {
        // ---- weight -> bf16: wt2[k][p][co][c32], c = p*32+c32 ----
        const int i = (bid - 2816) * 256 + t;
        if (i < 9 * 2 * 64 * 32) {
            const int k   = i >> 12;
            const int r   = i & 4095;
            const int p   = r >> 11;
            const int r2  = r & 2047;
            const int co  = r2 >> 5;
            const int c32 = r2 & 31;
            const int c   = p * 32 + c32;
            wt[i] = f2bf(w[co * KPOS + c * 9 + k]);
        }
    }
}

// ================= main: zero-LDS, explicit half-tap register pipeline =====
// lane = g*16 + pxl : pxl = A row (pixel), g8 = k-frag col -> bilinear output
// IS the MFMA A-fragment. 18 half-taps; half h = (tap h>>1, pass h&1).
// While half h computes (combine+4 MFMA), half h+1's 4 gathers + 4 B-loads
// are in flight in the cr[(h+1)&1]/bf[(h+1)&1] register buffers.
__global__ __launch_bounds__(256, 4)
void dcn_pipe(const unsigned short* __restrict__ xT,
              const unsigned* __restrict__ mOffs,
              const f16x4* __restrict__ mWts,
              const float* __restrict__ bias,
              const unsigned short* __restrict__ wt2,
              float* __restrict__ out)
{
    const int t    = threadIdx.x;
    const int bid  = blockIdx.x;
    const int wk   = ((bid & 7) << 7) | (bid >> 3);   // XCD-chunked swizzle
    const int xh   = wk & 1;
    const int ho   = (wk >> 1) & 127;
    const int b    = wk >> 8;
    const int cq   = t >> 6;
    const int lane = t & 63;
    const int pxl  = lane & 15;          // pixel = A row
    const int g8   = (lane >> 4) * 8;    // k-frag col oct

    f32x4 acc[4];
    #pragma unroll
    for (int i = 0; i < 4; ++i) acc[i] = (f32x4){0.f, 0.f, 0.f, 0.f};

    const unsigned short* xTb = xT + (size_t)b * HW * 64;
    const int gp    = ho * W_ + xh * 64 + cq * 16 + pxl;
    const int mbase = (b * 9) << 14;

    // pipeline state (all statically indexed after full unroll)
    unsigned mO[2]; f16x4 mW[2];
    int      adr[2][4];                  // corner base offsets for 2 taps
    bf16x8   cr[2][4];                   // gather dbuf (4 corners per half)
    bf16x8   bf[2][4];                   // B-frag dbuf (4 nt per half)
    float    w0 = 0.f, w1 = 0.f, w2 = 0.f, w3 = 0.f;

    auto loadmeta = [&](int k, int s) {
        const int mi = mbase + (k << 14) + gp;
        mO[s] = mOffs[mi];
        mW[s] = mWts[mi];
    };
    auto decode = [&](int s) {
        const unsigned pk = mO[s];
        const int y0 = (pk & 255) << 7,  y1 = ((pk >> 8) & 255) << 7;
        const int x0 = (pk >> 16) & 255, x1 = (int)(pk >> 24);
        adr[s][0] = ((y0 | x0) << 6) + g8;
        adr[s][1] = ((y0 | x1) << 6) + g8;
        adr[s][2] = ((y1 | x0) << 6) + g8;
        adr[s][3] = ((y1 | x1) << 6) + g8;
    };
    auto issue = [&](int h) {            // fill cr[h&1], bf[h&1] for half h
        const int k = h >> 1, p = h & 1, s = h & 1;
        const int po = p * 32;
        #pragma unroll
        for (int cn = 0; cn < 4; ++cn)
            cr[s][cn] = *(const bf16x8*)(xTb + adr[k & 1][cn] + po);
        const unsigned short* wp = wt2 + ((k * 2 + p) * 64 + pxl) * 32 + g8;
        #pragma unroll
        for (int nt = 0; nt < 4; ++nt)
            bf[s][nt] = *(const bf16x8*)(wp + nt * 512);
    };

    // ---- prologue ----
    loadmeta(0, 0);
    loadmeta(1, 1);
    decode(0);
    issue(0);

    #pragma unroll
    for (int h = 0; h < 18; ++h) {
        const int s = h & 1;
        const int k = h >> 1;
        const int p = h & 1;

        // issue next half's loads before consuming current
        if (h < 17) {
            const int hn = h + 1;
            if ((hn & 1) == 0) decode((hn >> 1) & 1);   // new tap: addresses
            issue(hn);
        }

        // per-tap bilinear weights
        if (p == 0) {
            w0 = (float)mW[k & 1][0];
            w1 = (float)mW[k & 1][1];
            w2 = (float)mW[k & 1][2];
            w3 = (float)mW[k & 1][3];
        }

        // combine 4 corners -> A fragment (8 ch, this half's 32 k-cols)
        union { bf16x8 v; unsigned u[4]; } a;
        {
            const unsigned* u0 = (const unsigned*)&cr[s][0];
            const unsigned* u1 = (const unsigned*)&cr[s][1];
            const unsigned* u2 = (const unsigned*)&cr[s][2];
            const unsigned* u3 = (const unsigned*)&cr[s][3];
            #pragma unroll
            for (int j = 0; j < 4; ++j) {
                const float lo = w0*bfl(u0[j]) + w1*bfl(u1[j])
                               + w2*bfl(u2[j]) + w3*bfl(u3[j]);
                const float hi = w0*bfh(u0[j]) + w1*bfh(u1[j])
                               + w2*bfh(u2[j]) + w3*bfh(u3[j]);
                a.u[j] = cvt_pk_bf16(lo, hi);
            }
        }

        // 4 MFMAs for this half's K=32
        #pragma unroll
        for (int nt = 0; nt < 4; ++nt)
            acc[nt] = __builtin_amdgcn_mfma_f32_16x16x32_bf16(a.v, bf[s][nt], acc[nt], 0, 0, 0);

        // refill meta pipeline after tap k fully consumed
        if (p == 1 && k + 2 < 9) loadmeta(k + 2, k & 1);
    }

    // ---- epilogue: D col = lane&15 (co), row = (lane>>4)*4+j (pixel) ----
    const int px0 = cq * 16 + (lane >> 4) * 4;
    #pragma unroll
    for (int nt = 0; nt < 4; ++nt) {
        const int co = nt * 16 + (lane & 15);
        const float bb = bias[co];
        float4 r;
        r.x = acc[nt][0] + bb;
        r.y = acc[nt][1] + bb;
        r.z = acc[nt][2] + bb;
        r.w = acc[nt][3] + bb;
        *(float4*)&out[(((size_t)b * COUT_ + co) * H_ + ho) * W_ + xh * 64 + px0] = r;
    }
}

// ================= fallback path (ws too small): R4 kernels =================
__global__ __launch_bounds__(256)
void xpose_bf16(const float* __restrict__ x, unsigned short* __restrict__ xT)
{
    __shared__ unsigned short ld[64 * 132];
    const int t   = threadIdx.x;
    const int blk = blockIdx.x;
    const int b   = blk >> 7;
    const int y   = blk & 127;
    const float* src = x + (size_t)b * 64 * HW + y * W_;
    #pragma unroll
    for (int i = 0; i < 8; ++i) {
        const int e4 = (t + i * 256) * 4;
        const int c  = e4 >> 7;
        const int x0 = e4 & 127;
        const float4 v = *(const float4*)(src + (size_t)c * HW + x0);
        unsigned short* d = &ld[c * 132 + x0];
        d[0] = f2bf(v.x); d[1] = f2bf(v.y); d[2] = f2bf(v.z); d[3] = f2bf(v.w);
    }
    __syncthreads();
    unsigned short* dst = xT + ((size_t)b * HW + (size_t)y * W_) * 64;
    #pragma unroll
    for (int i = 0; i < 4; ++i) {
        const int o    = (t + i * 256) * 8;
        const int xcol = o >> 6;
        const int c0   = o & 63;
        union { bf16x8 v; unsigned short u[8]; } pk;
        #pragma unroll
        for (int j = 0; j < 8; ++j) pk.u[j] = ld[(c0 + j) * 132 + xcol];
        *(bf16x8*)(dst + o) = pk.v;
    }
}

__global__ void prep_weight_fb(const float* __restrict__ w,
                               unsigned short* __restrict__ wt)
{
    const int i = blockIdx.x * 256 + threadIdx.x;
    if (i >= 9 * 64 * 64) return;
    const int k  = i >> 12;
    const int r  = i & 4095;
    const int co = r >> 6;
    const int c  = r & 63;
    wt[i] = f2bf(w[co * KPOS + c * 9 + k]);
}

__global__ __launch_bounds__(256, 4)
void dcn_mfma_nhwc(const unsigned short* __restrict__ xT,
                   const float* __restrict__ offset,
                   const float* __restrict__ mask,
                   const float* __restrict__ bias,
                   const unsigned short* __restrict__ wprep,
                   float* __restrict__ out)
{
    __shared__ unsigned short vP[2][64][72];
    __shared__ unsigned short Wk[2][64][72];
    const int t   = threadIdx.x;
    const int bid = blockIdx.x;
    const int wk  = ((bid & 7) << 7) | (bid >> 3);
    const int xh  = wk & 1;
    const int ho  = (wk >> 1) & 127;
    const int b   = wk >> 8;
    const int cq  = t >> 6;
    const int lane = t & 63;
    const int px_sub = lane >> 4;
    const int c4     = lane & 15;
    f32x4 acc[4];
    #pragma unroll
    for (int i = 0; i < 4; ++i) acc[i] = (f32x4){0.f, 0.f, 0.f, 0.f};
    const unsigned short* xTb = xT + (size_t)b * HW * 64;

    auto stage = [&](int k, int s) {
        int   idxs[4][4];
        float wts [4][4];
        #pragma unroll
        for (int it = 0; it < 4; ++it) {
            const int pl = (cq << 4) | (it << 2) | px_sub;
            const int wo = xh * 64 + pl;
            const int obase = ((b * 18 + 2 * k) * H_ + ho) * W_ + wo;
            const float dy = offset[obase];
            const float dx = offset[obase + HW];
            const float mm = mask[((b * 9 + k) * H_ + ho) * W_ + wo];
            const float py  = dy + (float)(k / 3) + (float)(ho - 1);
            const float pxx = dx + (float)(k % 3) + (float)(wo - 1);
            const float y0f = floorf(py), x0f = floorf(pxx);
            const float wy = py - y0f, wx = pxx - x0f;
            const int y0 = (int)y0f, x0 = (int)x0f;
            const int y1 = y0 + 1,  x1 = x0 + 1;
            const bool vy0 = (y0 >= 0) & (y0 < H_), vy1 = (y1 >= 0) & (y1 < H_);
            const bool vx0 = (x0 >= 0) & (x0 < W_), vx1 = (x1 >= 0) & (x1 < W_);
            const int cy0 = min(max(y0, 0), H_-1), cy1 = min(max(y1, 0), H_-1);
            const int cx0 = min(max(x0, 0), W_-1), cx1 = min(max(x1, 0), W_-1);
            idxs[it][0] = (cy0 * W_ + cx0) << 6;
            idxs[it][1] = (cy0 * W_ + cx1) << 6;
            idxs[it][2] = (cy1 * W_ + cx0) << 6;
            idxs[it][3] = (cy1 * W_ + cx1) << 6;
            wts[it][0] = (vy0 && vx0) ? (1.f - wy) * (1.f - wx) * mm : 0.f;
            wts[it][1] = (vy0 && vx1) ? (1.f - wy) * wx * mm         : 0.f;
            wts[it][2] = (vy1 && vx0) ? wy * (1.f - wx) * mm         : 0.f;
            wts[it][3] = (vy1 && vx1) ? wy * wx * mm                 : 0.f;
        }
        bf16x4 cr[4][4];
        #pragma unroll
        for (int it = 0; it < 4; ++it)
            #pragma unroll
            for (int cn = 0; cn < 4; ++cn)
                cr[it][cn] = *(const bf16x4*)(xTb + idxs[it][cn] + (c4 << 2));
        #pragma unroll
        for (int q = 0; q < 2; ++q) {
            const int j  = q * 2048 + t * 8;
            *(bf16x8*)&Wk[s][j >> 6][j & 63] = *(const bf16x8*)(wprep + k * 4096 + j);
        }
        #pragma unroll
        for (int it = 0; it < 4; ++it) {
            const int pl = (cq << 4) | (it << 2) | px_sub;
            union { bf16x4 v; unsigned short u[4]; } pk;
            #pragma unroll
            for (int j = 0; j < 4; ++j) {
                union { short s; unsigned short u; } s0{cr[it][0][j]}, s1{cr[it][1][j]},
                                                     s2{cr[it][2][j]}, s3{cr[it][3][j]};
                const float v = wts[it][0] * bfl(s0.u) + wts[it][1] * bfl(s1.u)
                              + wts[it][2] * bfl(s2.u) + wts[it][3] * bfl(s3.u);
                pk.u[j] = f2bf(v);
            }
            *(bf16x4*)&vP[s][pl][c4 << 2] = pk.v;
        }
    };
    auto domfma = [&](int s) {
        const int ra = cq * 16 + (lane & 15);
        const int kc = (lane >> 4) * 8;
        #pragma unroll
        for (int ks = 0; ks < 2; ++ks) {
            const int kcol = ks * 32 + kc;
            const bf16x8 a = *(const bf16x8*)&vP[s][ra][kcol];
            #pragma unroll
            for (int nt = 0; nt < 4; ++nt) {
                const bf16x8 bb = *(const bf16x8*)&Wk[s][nt * 16 + (lane & 15)][kcol];
                acc[nt] = __builtin_amdgcn_mfma_f32_16x16x32_bf16(a, bb, acc[nt], 0, 0, 0);
            }
        }
    };
    stage(0, 0);
    __syncthreads();
    for (int k = 0; k < 9; ++k) {
        const int s = k & 1;
        if (k < 8) stage(k + 1, s ^ 1);
        domfma(s);
        __syncthreads();
    }
    const int px0 = cq * 16 + (lane >> 4) * 4;
    #pragma unroll
    for (int nt = 0; nt < 4; ++nt) {
        const int co = nt * 16 + (lane & 15);
        const float bb = bias[co];
        float4 r;
        r.x = acc[nt][0] + bb;
        r.y = acc[nt][1] + bb;
        r.z = acc[nt][2] + bb;
        r.w = acc[nt][3] + bb;
        *(float4*)&out[(((size_t)b * COUT_ + co) * H_ + ho) * W_ + xh * 64 + px0] = r;
    }
}

extern "C" void kernel_launch(void* const* d_in, const int* in_sizes, int n_in,
                              void* d_out, int out_size, void* d_ws, size_t ws_size,
                              hipStream_t stream)
{
    const float* x      = (const float*)d_in[0];
    const float* offset = (const float*)d_in[1];
    const float* mask   = (const float*)d_in[2];
    const float* weight = (const float*)d_in[3];
    const float* bias   = (const float*)d_in[4];
    float* out = (float*)d_out;

    dim3 block(256);
    dim3 grid(B_ * H_ * 2);

    unsigned short* xT    = (unsigned short*)d_ws;
    unsigned short* wprep = xT + XT_USHORTS;

    if (ws_size >= WS_NEED3) {
        unsigned* mOffs = (unsigned*)((char*)d_ws + OFFS_BYTE);
        f16x4*    mWts  = (f16x4*)  ((char*)d_ws + WTS_BYTE);
        prep_all<<<dim3(2960), block, 0, stream>>>(x, offset, mask, weight,
                                                   xT, wprep, mOffs, mWts);
        dcn_pipe<<<grid, block, 0, stream>>>(xT, mOffs, mWts, bias, wprep, out);
    } else {
        xpose_bf16<<<dim3(B_ * H_), block, 0, stream>>>(x, xT);
        prep_weight_fb<<<dim3(144), block, 0, stream>>>(weight, wprep);
        dcn_mfma_nhwc<<<grid, block, 0, stream>>>(xT, offset, mask, bias, wprep, out);
    }
}

// Round 8
// 66.564 us; speedup vs baseline: 1.2325x; 1.0044x over previous
//
#include <hip/hip_runtime.h>

#define B_    4
#define CIN_  64
#define H_    128
#define W_    128
#define COUT_ 64
#define HW    (H_*W_)
#define KPOS  576

typedef __attribute__((ext_vector_type(8))) short bf16x8;
typedef __attribute__((ext_vector_type(4))) short bf16x4;
typedef __attribute__((ext_vector_type(4))) float f32x4;
typedef __attribute__((ext_vector_type(4))) _Float16 f16x4;

static __device__ __forceinline__ unsigned short f2bf(float f) {
    union { float f; unsigned u; } a; a.f = f;
    unsigned r = a.u + 0x7fffu + ((a.u >> 16) & 1u);   // RNE
    return (unsigned short)(r >> 16);
}
static __device__ __forceinline__ float bfl(unsigned u) {   // low bf16 -> f32
    union { unsigned x; float f; } a; a.x = u << 16; return a.f;
}
static __device__ __forceinline__ float bfh(unsigned u) {   // high bf16 -> f32
    union { unsigned x; float f; } a; a.x = u & 0xffff0000u; return a.f;
}
static __device__ __forceinline__ unsigned cvt_pk_bf16(float lo, float hi) {
    unsigned r;
    asm("v_cvt_pk_bf16_f32 %0, %1, %2" : "=v"(r) : "v"(lo), "v"(hi));
    return r;
}

#define XT_USHORTS 4194304                       // B*HW*64 NHWC bf16 image
#define WP_USHORTS 36864                         // wt2[k][p][co][32c]
#define META_CNT   (B_*9*HW)                     // 589824
#define OFFS_BYTE  ((XT_USHORTS + WP_USHORTS) * 2)        // 8462336
#define WTS_BYTE   (OFFS_BYTE + META_CNT * 4)             // 10821632
#define WS_NEED3   ((size_t)(WTS_BYTE + META_CNT * 8))    // ~15.5 MB

// ================= fused prep: xpose | meta | weight in one launch =========
__global__ __launch_bounds__(256)
void prep_all(const float* __restrict__ x,
              const float* __restrict__ offset,
              const float* __restrict__ mask,
              const float* __restrict__ w,
              unsigned short* __restrict__ xT,
              unsigned short* __restrict__ wt,
              unsigned* __restrict__ mOffs,
              f16x4* __restrict__ mWts)
{
    const int bid = blockIdx.x;
    const int t   = threadIdx.x;

    if (bid < 512) {
        // ---- x NCHW f32 -> NHWC bf16 (one (b,y) row per block) ----
        __shared__ unsigned short ld[64 * 132];
        const int b = bid >> 7;
        const int y = bid & 127;
        const float* src = x + (size_t)b * 64 * HW + y * W_;
        #pragma unroll
        for (int i = 0; i < 8; ++i) {
            const int e4 = (t + i * 256) * 4;
            const int c  = e4 >> 7;
            const int x0 = e4 & 127;
            const float4 v = *(const float4*)(src + (size_t)c * HW + x0);
            unsigned short* d = &ld[c * 132 + x0];
            d[0] = f2bf(v.x); d[1] = f2bf(v.y); d[2] = f2bf(v.z); d[3] = f2bf(v.w);
        }
        __syncthreads();
        unsigned short* dst = xT + ((size_t)b * HW + (size_t)y * W_) * 64;
        #pragma unroll
        for (int i = 0; i < 4; ++i) {
            const int o    = (t + i * 256) * 8;
            const int xcol = o >> 6;
            const int c0   = o & 63;
            union { bf16x8 v; unsigned short u[8]; } pk;
            #pragma unroll
            for (int j = 0; j < 8; ++j) pk.u[j] = ld[(c0 + j) * 132 + xcol];
            *(bf16x8*)(dst + o) = pk.v;
        }
    } else if (bid < 2816) {
        // ---- sampling metadata per (b,tap,pixel) ----
        const int i  = (bid - 512) * 256 + t;
        const int gp = i & (HW - 1);
        const int bk = i >> 14;              // b*9 + k
        const int b  = bk / 9;
        const int k  = bk - b * 9;
        const int ho = gp >> 7, wo = gp & 127;
        const float dy = offset[(size_t)(b * 18 + 2 * k) * HW + gp];
        const float dx = offset[(size_t)(b * 18 + 2 * k + 1) * HW + gp];
        const float mm = mask[(size_t)bk * HW + gp];
        const float py  = dy + (float)(k / 3) + (float)(ho - 1);   // PAD=1
        const float pxx = dx + (float)(k % 3) + (float)(wo - 1);
        const float y0f = floorf(py), x0f = floorf(pxx);
        const float wy = py - y0f, wx = pxx - x0f;
        const int y0 = (int)y0f, x0 = (int)x0f;
        const int y1 = y0 + 1,  x1 = x0 + 1;
        const bool vy0 = (y0 >= 0) & (y0 < H_), vy1 = (y1 >= 0) & (y1 < H_);
        const bool vx0 = (x0 >= 0) & (x0 < W_), vx1 = (x1 >= 0) & (x1 < W_);
        const int cy0 = min(max(y0, 0), H_-1), cy1 = min(max(y1, 0), H_-1);
        const int cx0 = min(max(x0, 0), W_-1), cx1 = min(max(x1, 0), W_-1);
        mOffs[i] = (unsigned)cy0 | ((unsigned)cy1 << 8)
                 | ((unsigned)cx0 << 16) | ((unsigned)cx1 << 24);
        f16x4 wv;
        wv[0] = (_Float16)((vy0 && vx0) ? (1.f - wy) * (1.f - wx) * mm : 0.f);
        wv[1] = (_Float16)((vy0 && vx1) ? (1.f - wy) * wx * mm         : 0.f);
        wv[2] = (_Float16)((vy1 && vx0) ? wy * (1.f - wx) * mm         : 0.f);
        wv[3] = (_Float16)((vy1 && vx1) ? wy * wx * mm                 : 0.f);
        mWts[i] = wv;
    } else {
        // ---- weight -> bf16: wt2[k][p][co][c32], c = p*32+c32 ----
        const int i = (bid - 2816) * 256 + t;
        if (i < 9 * 2 * 64 * 32) {
            const int k   = i >> 12;
            const int r   = i & 4095;
            const int p   = r >> 11;
            const int r2  = r & 2047;
            const int co  = r2 >> 5;
            const int c32 = r2 & 31;
            const int c   = p * 32 + c32;
            wt[i] = f2bf(w[co * KPOS + c * 9 + k]);
        }
    }
}

// ================= main: zero-LDS half-tap register pipeline, FENCED =======
// lane = g*16 + pxl : bilinear output IS the MFMA A-fragment.
// 18 half-taps; while half h computes (combine + 4 MFMA), half h+1's
// 4 gathers + 4 B-loads are in flight. sched_barrier(0) after each issue
// prevents the compiler from sinking the prefetch loads to their uses
// (R7 failure mode: VGPR collapsed to 48, pipeline serialized).
__global__ __launch_bounds__(256, 3)
void dcn_pipe(const unsigned short* __restrict__ xT,
              const unsigned* __restrict__ mOffs,
              const f16x4* __restrict__ mWts,
              const float* __restrict__ bias,
              const unsigned short* __restrict__ wt2,
              float* __restrict__ out)
{
    const int t    = threadIdx.x;
    const int bid  = blockIdx.x;
    const int wk   = ((bid & 7) << 7) | (bid >> 3);   // XCD-chunked swizzle
    const int xh   = wk & 1;
    const int ho   = (wk >> 1) & 127;
    const int b    = wk >> 8;
    const int cq   = t >> 6;
    const int lane = t & 63;
    const int pxl  = lane & 15;          // pixel = A row
    const int g8   = (lane >> 4) * 8;    // k-frag col oct

    f32x4 acc[4];
    #pragma unroll
    for (int i = 0; i < 4; ++i) acc[i] = (f32x4){0.f, 0.f, 0.f, 0.f};

    const unsigned short* xTb = xT + (size_t)b * HW * 64;
    const int gp    = ho * W_ + xh * 64 + cq * 16 + pxl;
    const int mbase = (b * 9) << 14;

    // pipeline state (statically indexed after full unroll)
    unsigned mO[2]; f16x4 mW[2];
    int      adr[2][4];                  // corner base offsets for 2 taps
    bf16x8   cr[2][4];                   // gather dbuf (4 corners per half)
    bf16x8   bf[2][4];                   // B-frag dbuf (4 nt per half)
    float    w0 = 0.f, w1 = 0.f, w2 = 0.f, w3 = 0.f;

    auto loadmeta = [&](int k, int s) {
        const int mi = mbase + (k << 14) + gp;
        mO[s] = mOffs[mi];
        mW[s] = mWts[mi];
    };
    auto decode = [&](int s) {
        const unsigned pk = mO[s];
        const int y0 = (pk & 255) << 7,  y1 = ((pk >> 8) & 255) << 7;
        const int x0 = (pk >> 16) & 255, x1 = (int)(pk >> 24);
        adr[s][0] = ((y0 | x0) << 6) + g8;
        adr[s][1] = ((y0 | x1) << 6) + g8;
        adr[s][2] = ((y1 | x0) << 6) + g8;
        adr[s][3] = ((y1 | x1) << 6) + g8;
    };
    auto issue = [&](int h) {            // fill cr[h&1], bf[h&1] for half h
        const int k = h >> 1, p = h & 1, s = h & 1;
        const int po = p * 32;
        #pragma unroll
        for (int cn = 0; cn < 4; ++cn)
            cr[s][cn] = *(const bf16x8*)(xTb + adr[k & 1][cn] + po);
        const unsigned short* wp = wt2 + ((k * 2 + p) * 64 + pxl) * 32 + g8;
        #pragma unroll
        for (int nt = 0; nt < 4; ++nt)
            bf[s][nt] = *(const bf16x8*)(wp + nt * 512);
    };

    // ---- prologue ----
    loadmeta(0, 0);
    loadmeta(1, 1);
    decode(0);
    issue(0);
    __builtin_amdgcn_sched_barrier(0);   // pin prologue loads before loop

    #pragma unroll
    for (int h = 0; h < 18; ++h) {
        const int s = h & 1;
        const int k = h >> 1;
        const int p = h & 1;

        // issue next half's loads; the fence pins them HERE so they fly
        // while the current half computes below.
        if (h < 17) {
            const int hn = h + 1;
            if ((hn & 1) == 0) decode((hn >> 1) & 1);   // new tap: addresses
            issue(hn);
        }
        __builtin_amdgcn_sched_barrier(0);

        // per-tap bilinear weights
        if (p == 0) {
            w0 = (float)mW[k & 1][0];
            w1 = (float)mW[k & 1][1];
            w2 = (float)mW[k & 1][2];
            w3 = (float)mW[k & 1][3];
        }

        // combine 4 corners -> A fragment (8 ch, this half's 32 k-cols)
        union { bf16x8 v; unsigned u[4]; } a;
        {
            const unsigned* u0 = (const unsigned*)&cr[s][0];
            const unsigned* u1 = (const unsigned*)&cr[s][1];
            const unsigned* u2 = (const unsigned*)&cr[s][2];
            const unsigned* u3 = (const unsigned*)&cr[s][3];
            #pragma unroll
            for (int j = 0; j < 4; ++j) {
                const float lo = w0*bfl(u0[j]) + w1*bfl(u1[j])
                               + w2*bfl(u2[j]) + w3*bfl(u3[j]);
                const float hi = w0*bfh(u0[j]) + w1*bfh(u1[j])
                               + w2*bfh(u2[j]) + w3*bfh(u3[j]);
                a.u[j] = cvt_pk_bf16(lo, hi);
            }
        }

        // 4 MFMAs for this half's K=32
        #pragma unroll
        for (int nt = 0; nt < 4; ++nt)
            acc[nt] = __builtin_amdgcn_mfma_f32_16x16x32_bf16(a.v, bf[s][nt], acc[nt], 0, 0, 0);

        // refill meta pipeline after tap k fully consumed
        if (p == 1 && k + 2 < 9) loadmeta(k + 2, k & 1);
        __builtin_amdgcn_sched_barrier(0);
    }

    // ---- epilogue: D col = lane&15 (co), row = (lane>>4)*4+j (pixel) ----
    const int px0 = cq * 16 + (lane >> 4) * 4;
    #pragma unroll
    for (int nt = 0; nt < 4; ++nt) {
        const int co = nt * 16 + (lane & 15);
        const float bb = bias[co];
        float4 r;
        r.x = acc[nt][0] + bb;
        r.y = acc[nt][1] + bb;
        r.z = acc[nt][2] + bb;
        r.w = acc[nt][3] + bb;
        *(float4*)&out[(((size_t)b * COUT_ + co) * H_ + ho) * W_ + xh * 64 + px0] = r;
    }
}

// ================= fallback path (ws too small): R4 kernels =================
__global__ __launch_bounds__(256)
void xpose_bf16(const float* __restrict__ x, unsigned short* __restrict__ xT)
{
    __shared__ unsigned short ld[64 * 132];
    const int t   = threadIdx.x;
    const int blk = blockIdx.x;
    const int b   = blk >> 7;
    const int y   = blk & 127;
    const float* src = x + (size_t)b * 64 * HW + y * W_;
    #pragma unroll
    for (int i = 0; i < 8; ++i) {
        const int e4 = (t + i * 256) * 4;
        const int c  = e4 >> 7;
        const int x0 = e4 & 127;
        const float4 v = *(const float4*)(src + (size_t)c * HW + x0);
        unsigned short* d = &ld[c * 132 + x0];
        d[0] = f2bf(v.x); d[1] = f2bf(v.y); d[2] = f2bf(v.z); d[3] = f2bf(v.w);
    }
    __syncthreads();
    unsigned short* dst = xT + ((size_t)b * HW + (size_t)y * W_) * 64;
    #pragma unroll
    for (int i = 0; i < 4; ++i) {
        const int o    = (t + i * 256) * 8;
        const int xcol = o >> 6;
        const int c0   = o & 63;
        union { bf16x8 v; unsigned short u[8]; } pk;
        #pragma unroll
        for (int j = 0; j < 8; ++j) pk.u[j] = ld[(c0 + j) * 132 + xcol];
        *(bf16x8*)(dst + o) = pk.v;
    }
}

__global__ void prep_weight_fb(const float* __restrict__ w,
                               unsigned short* __restrict__ wt)
{
    const int i = blockIdx.x * 256 + threadIdx.x;
    if (i >= 9 * 64 * 64) return;
    const int k  = i >> 12;
    const int r  = i & 4095;
    const int co = r >> 6;
    const int c  = r & 63;
    wt[i] = f2bf(w[co * KPOS + c * 9 + k]);
}

__global__ __launch_bounds__(256, 4)
void dcn_mfma_nhwc(const unsigned short* __restrict__ xT,
                   const float* __restrict__ offset,
                   const float* __restrict__ mask,
                   const float* __restrict__ bias,
                   const unsigned short* __restrict__ wprep,
                   float* __restrict__ out)
{
    __shared__ unsigned short vP[2][64][72];
    __shared__ unsigned short Wk[2][64][72];
    const int t   = threadIdx.x;
    const int bid = blockIdx.x;
    const int wk  = ((bid & 7) << 7) | (bid >> 3);
    const int xh  = wk & 1;
    const int ho  = (wk >> 1) & 127;
    const int b   = wk >> 8;
    const int cq  = t >> 6;
    const int lane = t & 63;
    const int px_sub = lane >> 4;
    const int c4     = lane & 15;
    f32x4 acc[4];
    #pragma unroll
    for (int i = 0; i < 4; ++i) acc[i] = (f32x4){0.f, 0.f, 0.f, 0.f};
    const unsigned short* xTb = xT + (size_t)b * HW * 64;

    auto stage = [&](int k, int s) {
        int   idxs[4][4];
        float wts [4][4];
        #pragma unroll
        for (int it = 0; it < 4; ++it) {
            const int pl = (cq << 4) | (it << 2) | px_sub;
            const int wo = xh * 64 + pl;
            const int obase = ((b * 18 + 2 * k) * H_ + ho) * W_ + wo;
            const float dy = offset[obase];
            const float dx = offset[obase + HW];
            const float mm = mask[((b * 9 + k) * H_ + ho) * W_ + wo];
            const float py  = dy + (float)(k / 3) + (float)(ho - 1);
            const float pxx = dx + (float)(k % 3) + (float)(wo - 1);
            const float y0f = floorf(py), x0f = floorf(pxx);
            const float wy = py - y0f, wx = pxx - x0f;
            const int y0 = (int)y0f, x0 = (int)x0f;
            const int y1 = y0 + 1,  x1 = x0 + 1;
            const bool vy0 = (y0 >= 0) & (y0 < H_), vy1 = (y1 >= 0) & (y1 < H_);
            const bool vx0 = (x0 >= 0) & (x0 < W_), vx1 = (x1 >= 0) & (x1 < W_);
            const int cy0 = min(max(y0, 0), H_-1), cy1 = min(max(y1, 0), H_-1);
            const int cx0 = min(max(x0, 0), W_-1), cx1 = min(max(x1, 0), W_-1);
            idxs[it][0] = (cy0 * W_ + cx0) << 6;
            idxs[it][1] = (cy0 * W_ + cx1) << 6;
            idxs[it][2] = (cy1 * W_ + cx0) << 6;
            idxs[it][3] = (cy1 * W_ + cx1) << 6;
            wts[it][0] = (vy0 && vx0) ? (1.f - wy) * (1.f - wx) * mm : 0.f;
            wts[it][1] = (vy0 && vx1) ? (1.f - wy) * wx * mm         : 0.f;
            wts[it][2] = (vy1 && vx0) ? wy * (1.f - wx) * mm         : 0.f;
            wts[it][3] = (vy1 && vx1) ? wy * wx * mm                 : 0.f;
        }
        bf16x4 cr[4][4];
        #pragma unroll
        for (int it = 0; it < 4; ++it)
            #pragma unroll
            for (int cn = 0; cn < 4; ++cn)
                cr[it][cn] = *(const bf16x4*)(xTb + idxs[it][cn] + (c4 << 2));
        #pragma unroll
        for (int q = 0; q < 2; ++q) {
            const int j  = q * 2048 + t * 8;
            *(bf16x8*)&Wk[s][j >> 6][j & 63] = *(const bf16x8*)(wprep + k * 4096 + j);
        }
        #pragma unroll
        for (int it = 0; it < 4; ++it) {
            const int pl = (cq << 4) | (it << 2) | px_sub;
            union { bf16x4 v; unsigned short u[4]; } pk;
            #pragma unroll
            for (int j = 0; j < 4; ++j) {
                union { short s; unsigned short u; } s0{cr[it][0][j]}, s1{cr[it][1][j]},
                                                     s2{cr[it][2][j]}, s3{cr[it][3][j]};
                const float v = wts[it][0] * bfl(s0.u) + wts[it][1] * bfl(s1.u)
                              + wts[it][2] * bfl(s2.u) + wts[it][3] * bfl(s3.u);
                pk.u[j] = f2bf(v);
            }
            *(bf16x4*)&vP[s][pl][c4 << 2] = pk.v;
        }
    };
    auto domfma = [&](int s) {
        const int ra = cq * 16 + (lane & 15);
        const int kc = (lane >> 4) * 8;
        #pragma unroll
        for (int ks = 0; ks < 2; ++ks) {
            const int kcol = ks * 32 + kc;
            const bf16x8 a = *(const bf16x8*)&vP[s][ra][kcol];
            #pragma unroll
            for (int nt = 0; nt < 4; ++nt) {
                const bf16x8 bb = *(const bf16x8*)&Wk[s][nt * 16 + (lane & 15)][kcol];
                acc[nt] = __builtin_amdgcn_mfma_f32_16x16x32_bf16(a, bb, acc[nt], 0, 0, 0);
            }
        }
    };
    stage(0, 0);
    __syncthreads();
    for (int k = 0; k < 9; ++k) {
        const int s = k & 1;
        if (k < 8) stage(k + 1, s ^ 1);
        domfma(s);
        __syncthreads();
    }
    const int px0 = cq * 16 + (lane >> 4) * 4;
    #pragma unroll
    for (int nt = 0; nt < 4; ++nt) {
        const int co = nt * 16 + (lane & 15);
        const float bb = bias[co];
        float4 r;
        r.x = acc[nt][0] + bb;
        r.y = acc[nt][1] + bb;
        r.z = acc[nt][2] + bb;
        r.w = acc[nt][3] + bb;
        *(float4*)&out[(((size_t)b * COUT_ + co) * H_ + ho) * W_ + xh * 64 + px0] = r;
    }
}

extern "C" void kernel_launch(void* const* d_in, const int* in_sizes, int n_in,
                              void* d_out, int out_size, void* d_ws, size_t ws_size,
                              hipStream_t stream)
{
    const float* x      = (const float*)d_in[0];
    const float* offset = (const float*)d_in[1];
    const float* mask   = (const float*)d_in[2];
    const float* weight = (const float*)d_in[3];
    const float* bias   = (const float*)d_in[4];
    float* out = (float*)d_out;

    dim3 block(256);
    dim3 grid(B_ * H_ * 2);

    unsigned short* xT    = (unsigned short*)d_ws;
    unsigned short* wprep = xT + XT_USHORTS;

    if (ws_size >= WS_NEED3) {
        unsigned* mOffs = (unsigned*)((char*)d_ws + OFFS_BYTE);
        f16x4*    mWts  = (f16x4*)  ((char*)d_ws + WTS_BYTE);
        prep_all<<<dim3(2960), block, 0, stream>>>(x, offset, mask, weight,
                                                   xT, wprep, mOffs, mWts);
        dcn_pipe<<<grid, block, 0, stream>>>(xT, mOffs, mWts, bias, wprep, out);
    } else {
        xpose_bf16<<<dim3(B_ * H_), block, 0, stream>>>(x, xT);
        prep_weight_fb<<<dim3(144), block, 0, stream>>>(weight, wprep);
        dcn_mfma_nhwc<<<grid, block, 0, stream>>>(xT, offset, mask, bias, wprep, out);
    }
}